// Round 7
// baseline (905.797 us; speedup 1.0000x reference)
//
#include <hip/hip_runtime.h>
#include <hip/hip_bf16.h>

#define T_LEN 512
#define NSTEP 511
#define H 128
#define D_IN 64
#define D_OUT 64
#define XSTR 513
#define BUFN 2048   // ushorts per activation buffer (16 b-cols x 128 k)

typedef __attribute__((ext_vector_type(8))) short short8;
typedef __attribute__((ext_vector_type(4))) float f32x4;
typedef __attribute__((ext_vector_type(2))) unsigned int u32x2;

// Activation tile layout (bf16): elem (b in 0..15, k in 0..127) ->
//   ushort idx = (k>>5)*512 + ((k>>3)&3)*128 + b*8 + (k&7)
// Read: lane l takes short8 at 8*l + 512*s (byte 16*l) -> linear, conflict-free.
// A-frag f[i] of chunk s = W[row][32s + 8lg + i]  (validated convention r2-r6).

__device__ __forceinline__ float exp2_f(float x) {
  float r; asm("v_exp_f32 %0, %1" : "=v"(r) : "v"(x)); return r;
}
__device__ __forceinline__ float rcp_f(float x) {
  float r; asm("v_rcp_f32 %0, %1" : "=v"(r) : "v"(x)); return r;
}
__device__ __forceinline__ unsigned int cvtpk(float a, float b) {
  unsigned int r; asm("v_cvt_pk_bf16_f32 %0, %1, %2" : "=v"(r) : "v"(a), "v"(b)); return r;
}
__device__ __forceinline__ unsigned short f2bf(float f) {   // prologue-path only
  unsigned int x = __float_as_uint(f);
  x += 0x7fffu + ((x >> 16) & 1u);
  return (unsigned short)(x >> 16);
}
__device__ __forceinline__ float tanh_fast(float x) {
  float e = exp2_f(x * 2.8853900817779268f);   // e^(2x)
  float r = rcp_f(e + 1.0f);
  return __builtin_fmaf(-2.0f, r, 1.0f);
}
__device__ __forceinline__ float silu_f(float x) {
  float e = exp2_f(x * -1.4426950408889634f);  // e^(-x)
  return x * rcp_f(1.0f + e);
}

#define MFMA16(A, B, C) __builtin_amdgcn_mfma_f32_16x16x32_bf16(A, B, C, 0, 0, 0)

// split into two parallel acc chains (halved dependent-MFMA latency)
#define MATVEC1(BUF, WF, A)                                                   \
  {                                                                           \
    const unsigned short* _b = (BUF) + rdo;                                   \
    short8 q0 = *(const short8*)(_b);                                         \
    short8 q1 = *(const short8*)(_b + 512);                                   \
    short8 q2 = *(const short8*)(_b + 1024);                                  \
    short8 q3 = *(const short8*)(_b + 1536);                                  \
    f32x4 _ao = {0.f, 0.f, 0.f, 0.f};                                         \
    A   = MFMA16(WF[0], q0, A);                                               \
    _ao = MFMA16(WF[1], q1, _ao);                                             \
    A   = MFMA16(WF[2], q2, A);                                               \
    _ao = MFMA16(WF[3], q3, _ao);                                             \
    A = A + _ao;                                                              \
  }

// two matmuls sharing one B-tile read; each split into 2 chains
#define MATVEC2(BUF, WF0, WF1, A0, A1)                                        \
  {                                                                           \
    const unsigned short* _b = (BUF) + rdo;                                   \
    short8 q0 = *(const short8*)(_b);                                         \
    short8 q1 = *(const short8*)(_b + 512);                                   \
    short8 q2 = *(const short8*)(_b + 1024);                                  \
    short8 q3 = *(const short8*)(_b + 1536);                                  \
    f32x4 _a0o = {0.f, 0.f, 0.f, 0.f};                                        \
    f32x4 _a1o = {0.f, 0.f, 0.f, 0.f};                                        \
    A0   = MFMA16(WF0[0], q0, A0);                                            \
    A1   = MFMA16(WF1[0], q0, A1);                                            \
    _a0o = MFMA16(WF0[1], q1, _a0o);                                          \
    _a1o = MFMA16(WF1[1], q1, _a1o);                                          \
    A0   = MFMA16(WF0[2], q2, A0);                                            \
    A1   = MFMA16(WF1[2], q2, A1);                                            \
    _a0o = MFMA16(WF0[3], q3, _a0o);                                          \
    _a1o = MFMA16(WF1[3], q3, _a1o);                                          \
    A0 = A0 + _a0o;                                                           \
    A1 = A1 + _a1o;                                                           \
  }

#define WRITE1(BUF, V)                                                        \
  {                                                                           \
    u32x2 _p;                                                                 \
    _p.x = cvtpk(V[0], V[1]);                                                 \
    _p.y = cvtpk(V[2], V[3]);                                                 \
    *(u32x2*)((BUF) + wro) = _p;                                              \
  }

__global__ __launch_bounds__(512, 2) void rnnode_kernel(
    const float* __restrict__ x,     const float* __restrict__ span,
    const float* __restrict__ W_emb, const float* __restrict__ b_emb,
    const float* __restrict__ W_ih,  const float* __restrict__ b_ih,
    const float* __restrict__ W_hh,  const float* __restrict__ b_hh,
    const float* __restrict__ W1,    const float* __restrict__ b1p,
    const float* __restrict__ W2,    const float* __restrict__ b2p,
    const float* __restrict__ W_out, const float* __restrict__ b_out,
    float* __restrict__ out) {
  __shared__ __align__(16) unsigned short inbuf[2 * BUFN];
  __shared__ __align__(16) unsigned short h1buf[BUFN];
  __shared__ __align__(16) float wtmp[H * H];     // fp32 W2 (prologue + epilogue)
  __shared__ float xbuf[8 * XSTR];
  __shared__ float dtbuf[NSTEP];

  const int tid = threadIdx.x;
  const int w   = tid >> 6;     // wave 0..7, owns j-rows [16w, 16w+16)
  const int l   = tid & 63;
  const int l15 = l & 15;       // b-col
  const int lg  = l >> 4;
  const int b0  = blockIdx.x * 8;

  // ---- stage x, dt, W2 -> wtmp, zero activation buffers (h0 = 0) ----
  for (int i = tid; i < 8 * T_LEN; i += 512) {
    int b = i >> 9, t = i & (T_LEN - 1);
    xbuf[b * XSTR + t] = x[(b0 + b) * T_LEN + t];
  }
  for (int t = tid; t < NSTEP; t += 512) dtbuf[t] = span[t + 1] - span[t];
  for (int i = tid; i < 2 * BUFN; i += 512) inbuf[i] = 0;
  for (int i = tid; i < H * H; i += 512) wtmp[i] = W2[i];
  __syncthreads();

  const int row = 16 * w + l15;

  // ---- fused weight products W12 = W1*W2, Whh2 = W_hh*W2 (fp32 -> bf16 frags) ----
  short8 w12f[4], whh2f[4];
  {
    float acc[4][8];
#pragma unroll
    for (int s = 0; s < 4; ++s)
#pragma unroll
      for (int i = 0; i < 8; ++i) acc[s][i] = 0.f;
    for (int m = 0; m < H; ++m) {
      float a = W1[row * H + m];
      const f32x4* wr4 = (const f32x4*)(wtmp + m * H + 8 * lg);
#pragma unroll
      for (int s = 0; s < 4; ++s) {
        f32x4 lo = wr4[8 * s], hi = wr4[8 * s + 1];
#pragma unroll
        for (int i = 0; i < 4; ++i) {
          acc[s][i]     = __builtin_fmaf(a, lo[i], acc[s][i]);
          acc[s][4 + i] = __builtin_fmaf(a, hi[i], acc[s][4 + i]);
        }
      }
    }
#pragma unroll
    for (int s = 0; s < 4; ++s) {
      short8 f;
#pragma unroll
      for (int i = 0; i < 8; ++i) f[i] = (short)f2bf(acc[s][i]);
      w12f[s] = f;
    }
#pragma unroll
    for (int s = 0; s < 4; ++s)
#pragma unroll
      for (int i = 0; i < 8; ++i) acc[s][i] = 0.f;
    for (int m = 0; m < H; ++m) {
      float a = W_hh[row * H + m];
      const f32x4* wr4 = (const f32x4*)(wtmp + m * H + 8 * lg);
#pragma unroll
      for (int s = 0; s < 4; ++s) {
        f32x4 lo = wr4[8 * s], hi = wr4[8 * s + 1];
#pragma unroll
        for (int i = 0; i < 4; ++i) {
          acc[s][i]     = __builtin_fmaf(a, lo[i], acc[s][i]);
          acc[s][4 + i] = __builtin_fmaf(a, hi[i], acc[s][4 + i]);
        }
      }
    }
#pragma unroll
    for (int s = 0; s < 4; ++s) {
      short8 f;
#pragma unroll
      for (int i = 0; i < 8; ++i) f[i] = (short)f2bf(acc[s][i]);
      whh2f[s] = f;
    }
  }

  // ---- direct weight frags (bf16) ----
  short8 whhf[4], w1f[4];
#pragma unroll
  for (int s = 0; s < 4; ++s) {
    const float* p; short8 f;
    p = W_hh + row * H + 32 * s + 8 * lg;
#pragma unroll
    for (int i = 0; i < 8; ++i) f[i] = (short)f2bf(p[i]);
    whhf[s] = f;
    p = W1 + row * H + 32 * s + 8 * lg;
#pragma unroll
    for (int i = 0; i < 8; ++i) f[i] = (short)f2bf(p[i]);
    w1f[s] = f;
  }

  // ---- per-row vectors: e = W_ih*W_emb, c = W_ih*b_emb + b_ih + b_hh,
  //      c2 = W1*b2, whb2 = W_hh*b2, b1 ----
  f32x4 e_v, c_v, b1_v, c2_v, whb2_v;
#pragma unroll
  for (int r = 0; r < 4; ++r) {
    int j = 16 * w + 4 * lg + r;
    float e = 0.f, c = 0.f;
    const float* wr = W_ih + j * D_IN;
    for (int d = 0; d < D_IN; ++d) { float v = wr[d]; e += v * W_emb[d]; c += v * b_emb[d]; }
    e_v[r] = e; c_v[r] = c + b_ih[j] + b_hh[j];
    b1_v[r] = b1p[j];
    float cc2 = 0.f, cwh = 0.f;
    const float* w1r = W1 + j * H;
    const float* whr = W_hh + j * H;
    for (int m = 0; m < H; ++m) { float bb = b2p[m]; cc2 += w1r[m] * bb; cwh += whr[m] * bb; }
    c2_v[r] = cc2; whb2_v[r] = cwh;
  }

  __syncthreads();

  const int rdo = 8 * l;
  const int wro = (w >> 1) * 512 + ((2 * w + (lg >> 1)) & 3) * 128
                + 8 * l15 + 4 * (lg & 1);
  const float* xrow = xbuf + (l15 & 7) * XSTR;

  unsigned short* bA = inbuf;
  unsigned short* bB = inbuf + BUFN;

  // P_ = a0 for step 0 (dt_prev = 0; Whh2 contribution = 0 since bB zeroed)
  f32x4 P_;
#pragma unroll
  for (int r = 0; r < 4; ++r) P_[r] = __builtin_fmaf(xrow[0], e_v[r], c_v[r]);

  for (int t = 0; t < NSTEP; ++t) {
    const float dt  = dtbuf[t];
    const float xn  = xrow[t + 1];
    const float dt3 = dt * (1.f / 3.f);
    f32x4 a, h1, g, pn, s1, s2, s3, z1, z2;

    // ---- P0: a = P_ + Whh2*ssum_scaled ; h1 = tanh(a) ----
    a = P_;
    MATVEC1(bB, whh2f, a);
#pragma unroll
    for (int r = 0; r < 4; ++r) h1[r] = tanh_fast(a[r]);
    WRITE1(bA, h1);
    if (t == NSTEP - 1) {
      u32x2 p; p.x = cvtpk(h1[0], h1[1]); p.y = cvtpk(h1[2], h1[3]);
      *(u32x2*)(h1buf + wro) = p;
    }
    __syncthreads();

    // ---- P1: Gb = W1*h1 + b1 ; P_next = W_hh*h1 + (x_next*e + c + dt*whb2) ----
    g = b1_v;
#pragma unroll
    for (int r = 0; r < 4; ++r)
      pn[r] = __builtin_fmaf(dt, whb2_v[r], __builtin_fmaf(xn, e_v[r], c_v[r]));
    MATVEC2(bA, w1f, whhf, g, pn);
#pragma unroll
    for (int r = 0; r < 4; ++r) s1[r] = silu_f(g[r]);
    WRITE1(bB, s1);
    __syncthreads();

    // ---- P2: z1' = W12*s1 + c2 ; s2 = silu(Gb + dt/3 * z1') ----
    z1 = c2_v;
    MATVEC1(bB, w12f, z1);
#pragma unroll
    for (int r = 0; r < 4; ++r) s2[r] = silu_f(__builtin_fmaf(dt3, z1[r], g[r]));
    WRITE1(bA, s2);
    __syncthreads();

    // ---- P3: z2' = W12*s2 + c2 ; s3 = silu(Gb + dt*z2' - dt/3*z1') ----
    z2 = c2_v;
    MATVEC1(bA, w12f, z2);
#pragma unroll
    for (int r = 0; r < 4; ++r)
      s3[r] = silu_f(__builtin_fmaf(dt, z2[r], __builtin_fmaf(-dt3, z1[r], g[r])));
    WRITE1(bB, s3);
    __syncthreads();

    // ---- P4: z3' = W12*s3 + c2 ; s4 = silu(Gb + dt*(z1'-z2'+z3')) ;
    //          ssum_scaled = (s1 + 3(s2+s3) + s4) * dt/8 ----
    {
      f32x4 z3 = c2_v, ss;
      MATVEC1(bB, w12f, z3);
      const float dt8 = dt * 0.125f;
#pragma unroll
      for (int r = 0; r < 4; ++r) {
        float s4 = silu_f(__builtin_fmaf(dt, (z1[r] - z2[r]) + z3[r], g[r]));
        ss[r] = (__builtin_fmaf(3.f, s2[r] + s3[r], s1[r]) + s4) * dt8;
      }
      WRITE1(bA, ss);
    }
    __syncthreads();

    P_ = pn;
    unsigned short* tmp = bA; bA = bB; bB = tmp;
  }

  // ---- epilogue: out = W_out*h1_T + Wout2*ssum_scaled + dtl*(W_out*b2) + b_out ----
  // ssum_scaled (already *dtl/8) is in bB (last step's bA); h1_T in h1buf.
  {
    const int wo   = w & 3;
    const int orow = 16 * wo + l15;
    const int jo   = 16 * wo + 4 * lg;
    const float dtl = dtbuf[NSTEP - 1];

    short8 wout2f[4];
    {
      float acc[4][8];
#pragma unroll
      for (int s = 0; s < 4; ++s)
#pragma unroll
        for (int i = 0; i < 8; ++i) acc[s][i] = 0.f;
      for (int m = 0; m < H; ++m) {
        float a = W_out[orow * H + m];
        const f32x4* wr4 = (const f32x4*)(wtmp + m * H + 8 * lg);
#pragma unroll
        for (int s = 0; s < 4; ++s) {
          f32x4 lo = wr4[8 * s], hi = wr4[8 * s + 1];
#pragma unroll
          for (int i = 0; i < 4; ++i) {
            acc[s][i]     = __builtin_fmaf(a, lo[i], acc[s][i]);
            acc[s][4 + i] = __builtin_fmaf(a, hi[i], acc[s][4 + i]);
          }
        }
      }
#pragma unroll
      for (int s = 0; s < 4; ++s) {
        short8 f;
#pragma unroll
        for (int i = 0; i < 8; ++i) f[i] = (short)f2bf(acc[s][i]);
        wout2f[s] = f;
      }
    }
    short8 wof[4];
#pragma unroll
    for (int s = 0; s < 4; ++s) {
      const float* p = W_out + orow * H + 32 * s + 8 * lg;
      short8 f;
#pragma unroll
      for (int i = 0; i < 8; ++i) f[i] = (short)f2bf(p[i]);
      wof[s] = f;
    }
    f32x4 acc1, acc2;
#pragma unroll
    for (int r = 0; r < 4; ++r) {
      const float* wr = W_out + (jo + r) * H;
      float wb = 0.f;
      for (int m = 0; m < H; ++m) wb = __builtin_fmaf(wr[m], b2p[m], wb);
      acc1[r] = __builtin_fmaf(dtl, wb, b_out[jo + r]);
      acc2[r] = 0.f;
    }
    MATVEC1(h1buf, wof, acc1);
    MATVEC1(bB, wout2f, acc2);
    if (w < 4 && l15 < 8) {
#pragma unroll
      for (int r = 0; r < 4; ++r)
        out[(b0 + l15) * D_OUT + jo + r] = acc1[r] + acc2[r];
    }
  }
}

extern "C" void kernel_launch(void* const* d_in, const int* in_sizes, int n_in,
                              void* d_out, int out_size, void* d_ws, size_t ws_size,
                              hipStream_t stream) {
  (void)in_sizes; (void)n_in; (void)ws_size; (void)d_ws; (void)out_size;
  const float* x     = (const float*)d_in[0];
  const float* span  = (const float*)d_in[1];
  const float* W_emb = (const float*)d_in[2];
  const float* b_emb = (const float*)d_in[3];
  const float* W_ih  = (const float*)d_in[4];
  const float* b_ih  = (const float*)d_in[5];
  const float* W_hh  = (const float*)d_in[6];
  const float* b_hh  = (const float*)d_in[7];
  const float* W1    = (const float*)d_in[8];
  const float* b1    = (const float*)d_in[9];
  const float* W2    = (const float*)d_in[10];
  const float* b2    = (const float*)d_in[11];
  const float* W_out = (const float*)d_in[12];
  const float* b_out = (const float*)d_in[13];
  float* out = (float*)d_out;

  rnnode_kernel<<<dim3(256), dim3(512), 0, stream>>>(
      x, span, W_emb, b_emb, W_ih, b_ih, W_hh, b_hh,
      W1, b1, W2, b2, W_out, b_out, out);
}

// Round 8
// 892.619 us; speedup vs baseline: 1.0148x; 1.0148x over previous
//
#include <hip/hip_runtime.h>
#include <hip/hip_bf16.h>

#define T_LEN 512
#define NSTEP 511
#define H 128
#define D_IN 64
#define D_OUT 64
#define XSTR 513
#define BUFN 2048   // ushorts per activation buffer (16 b-cols x 128 k)

typedef __attribute__((ext_vector_type(8))) short short8;
typedef __attribute__((ext_vector_type(4))) float f32x4;
typedef __attribute__((ext_vector_type(2))) unsigned int u32x2;

// Activation tile layout (bf16): elem (b in 0..15, k in 0..127) ->
//   ushort idx = (k>>5)*512 + ((k>>3)&3)*128 + b*8 + (k&7)
// Read: lane l takes short8 at 8*l + 512*cs -> linear across wave, conflict-free.
// Chunk ROTATION: wave w consumes chunks in order cs = (s + w)&3; its weight
// frags are loaded pre-rotated so wf[s] pairs with chunk (s+w)&3. Spreads each
// wave's first-needed chunk across the post-barrier LDS drain (burst overlap).

__device__ __forceinline__ float exp2_f(float x) {
  float r; asm("v_exp_f32 %0, %1" : "=v"(r) : "v"(x)); return r;
}
__device__ __forceinline__ float rcp_f(float x) {
  float r; asm("v_rcp_f32 %0, %1" : "=v"(r) : "v"(x)); return r;
}
__device__ __forceinline__ unsigned int cvtpk(float a, float b) {
  unsigned int r; asm("v_cvt_pk_bf16_f32 %0, %1, %2" : "=v"(r) : "v"(a), "v"(b)); return r;
}
__device__ __forceinline__ unsigned short f2bf(float f) {   // prologue-path only
  unsigned int x = __float_as_uint(f);
  x += 0x7fffu + ((x >> 16) & 1u);
  return (unsigned short)(x >> 16);
}
__device__ __forceinline__ float tanh_fast(float x) {
  float e = exp2_f(x * 2.8853900817779268f);   // e^(2x)
  float r = rcp_f(e + 1.0f);
  return __builtin_fmaf(-2.0f, r, 1.0f);
}
__device__ __forceinline__ float silu_f(float x) {
  float e = exp2_f(x * -1.4426950408889634f);  // e^(-x)
  return x * rcp_f(1.0f + e);
}

#define MFMA16(A, B, C) __builtin_amdgcn_mfma_f32_16x16x32_bf16(A, B, C, 0, 0, 0)

// serial acc chain (r6 form; r7 split-chain regressed), rotated chunk order
#define MATVEC1(BUF, WF, A)                                                   \
  {                                                                           \
    const unsigned short* _b = (BUF) + rdo;                                   \
    short8 q0 = *(const short8*)(_b + o0);                                    \
    short8 q1 = *(const short8*)(_b + o1);                                    \
    short8 q2 = *(const short8*)(_b + o2);                                    \
    short8 q3 = *(const short8*)(_b + o3);                                    \
    A = MFMA16(WF[0], q0, A);                                                 \
    A = MFMA16(WF[1], q1, A);                                                 \
    A = MFMA16(WF[2], q2, A);                                                 \
    A = MFMA16(WF[3], q3, A);                                                 \
  }

// two matmuls sharing one B-tile read (serial chains)
#define MATVEC2(BUF, WF0, WF1, A0, A1)                                        \
  {                                                                           \
    const unsigned short* _b = (BUF) + rdo;                                   \
    short8 q0 = *(const short8*)(_b + o0);                                    \
    short8 q1 = *(const short8*)(_b + o1);                                    \
    short8 q2 = *(const short8*)(_b + o2);                                    \
    short8 q3 = *(const short8*)(_b + o3);                                    \
    A0 = MFMA16(WF0[0], q0, A0);                                              \
    A1 = MFMA16(WF1[0], q0, A1);                                              \
    A0 = MFMA16(WF0[1], q1, A0);                                              \
    A1 = MFMA16(WF1[1], q1, A1);                                              \
    A0 = MFMA16(WF0[2], q2, A0);                                              \
    A1 = MFMA16(WF1[2], q2, A1);                                              \
    A0 = MFMA16(WF0[3], q3, A0);                                              \
    A1 = MFMA16(WF1[3], q3, A1);                                              \
  }

#define WRITE1(BUF, V)                                                        \
  {                                                                           \
    u32x2 _p;                                                                 \
    _p.x = cvtpk(V[0], V[1]);                                                 \
    _p.y = cvtpk(V[2], V[3]);                                                 \
    *(u32x2*)((BUF) + wro) = _p;                                              \
  }

__global__ __launch_bounds__(512, 2) void rnnode_kernel(
    const float* __restrict__ x,     const float* __restrict__ span,
    const float* __restrict__ W_emb, const float* __restrict__ b_emb,
    const float* __restrict__ W_ih,  const float* __restrict__ b_ih,
    const float* __restrict__ W_hh,  const float* __restrict__ b_hh,
    const float* __restrict__ W1,    const float* __restrict__ b1p,
    const float* __restrict__ W2,    const float* __restrict__ b2p,
    const float* __restrict__ W_out, const float* __restrict__ b_out,
    float* __restrict__ out) {
  __shared__ __align__(16) unsigned short inbuf[2 * BUFN];
  __shared__ __align__(16) unsigned short h1buf[BUFN];
  __shared__ __align__(16) float wtmp[H * H];     // fp32 W2 (prologue + epilogue)
  __shared__ float xbuf[8 * XSTR];
  __shared__ float dtbuf[NSTEP];

  const int tid = threadIdx.x;
  const int w   = tid >> 6;     // wave 0..7, owns j-rows [16w, 16w+16)
  const int l   = tid & 63;
  const int l15 = l & 15;       // b-col
  const int lg  = l >> 4;
  const int b0  = blockIdx.x * 8;
  const int rot = w & 3;        // chunk rotation

  // rotated chunk byte offsets (in ushorts)
  const int o0 = ((rot + 0) & 3) * 512;
  const int o1 = ((rot + 1) & 3) * 512;
  const int o2 = ((rot + 2) & 3) * 512;
  const int o3 = ((rot + 3) & 3) * 512;

  // ---- stage x, dt, W2 -> wtmp, zero activation buffers (h0 = 0) ----
  for (int i = tid; i < 8 * T_LEN; i += 512) {
    int b = i >> 9, t = i & (T_LEN - 1);
    xbuf[b * XSTR + t] = x[(b0 + b) * T_LEN + t];
  }
  for (int t = tid; t < NSTEP; t += 512) dtbuf[t] = span[t + 1] - span[t];
  for (int i = tid; i < 2 * BUFN; i += 512) inbuf[i] = 0;
  for (int i = tid; i < H * H; i += 512) wtmp[i] = W2[i];
  __syncthreads();

  const int row = 16 * w + l15;

  // ---- fused weight products W12 = W1*W2, Whh2 = W_hh*W2 (fp32 -> bf16 frags),
  //      stored PRE-ROTATED: wf[s] holds chunk (s+rot)&3 ----
  short8 w12f[4], whh2f[4];
  {
    float acc[4][8];
#pragma unroll
    for (int s = 0; s < 4; ++s)
#pragma unroll
      for (int i = 0; i < 8; ++i) acc[s][i] = 0.f;
    for (int m = 0; m < H; ++m) {
      float a = W1[row * H + m];
      const f32x4* wr4 = (const f32x4*)(wtmp + m * H + 8 * lg);
#pragma unroll
      for (int s = 0; s < 4; ++s) {
        const int cs = (s + rot) & 3;
        f32x4 lo = wr4[8 * cs], hi = wr4[8 * cs + 1];
#pragma unroll
        for (int i = 0; i < 4; ++i) {
          acc[s][i]     = __builtin_fmaf(a, lo[i], acc[s][i]);
          acc[s][4 + i] = __builtin_fmaf(a, hi[i], acc[s][4 + i]);
        }
      }
    }
#pragma unroll
    for (int s = 0; s < 4; ++s) {
      short8 f;
#pragma unroll
      for (int i = 0; i < 8; ++i) f[i] = (short)f2bf(acc[s][i]);
      w12f[s] = f;
    }
#pragma unroll
    for (int s = 0; s < 4; ++s)
#pragma unroll
      for (int i = 0; i < 8; ++i) acc[s][i] = 0.f;
    for (int m = 0; m < H; ++m) {
      float a = W_hh[row * H + m];
      const f32x4* wr4 = (const f32x4*)(wtmp + m * H + 8 * lg);
#pragma unroll
      for (int s = 0; s < 4; ++s) {
        const int cs = (s + rot) & 3;
        f32x4 lo = wr4[8 * cs], hi = wr4[8 * cs + 1];
#pragma unroll
        for (int i = 0; i < 4; ++i) {
          acc[s][i]     = __builtin_fmaf(a, lo[i], acc[s][i]);
          acc[s][4 + i] = __builtin_fmaf(a, hi[i], acc[s][4 + i]);
        }
      }
    }
#pragma unroll
    for (int s = 0; s < 4; ++s) {
      short8 f;
#pragma unroll
      for (int i = 0; i < 8; ++i) f[i] = (short)f2bf(acc[s][i]);
      whh2f[s] = f;
    }
  }

  // ---- direct weight frags (bf16), pre-rotated ----
  short8 whhf[4], w1f[4];
#pragma unroll
  for (int s = 0; s < 4; ++s) {
    const int cs = (s + rot) & 3;
    const float* p; short8 f;
    p = W_hh + row * H + 32 * cs + 8 * lg;
#pragma unroll
    for (int i = 0; i < 8; ++i) f[i] = (short)f2bf(p[i]);
    whhf[s] = f;
    p = W1 + row * H + 32 * cs + 8 * lg;
#pragma unroll
    for (int i = 0; i < 8; ++i) f[i] = (short)f2bf(p[i]);
    w1f[s] = f;
  }

  // ---- per-row vectors: e = W_ih*W_emb, c = W_ih*b_emb + b_ih + b_hh,
  //      c2 = W1*b2, whb2 = W_hh*b2, b1 ----
  f32x4 e_v, c_v, b1_v, c2_v, whb2_v;
#pragma unroll
  for (int r = 0; r < 4; ++r) {
    int j = 16 * w + 4 * lg + r;
    float e = 0.f, c = 0.f;
    const float* wr = W_ih + j * D_IN;
    for (int d = 0; d < D_IN; ++d) { float v = wr[d]; e += v * W_emb[d]; c += v * b_emb[d]; }
    e_v[r] = e; c_v[r] = c + b_ih[j] + b_hh[j];
    b1_v[r] = b1p[j];
    float cc2 = 0.f, cwh = 0.f;
    const float* w1r = W1 + j * H;
    const float* whr = W_hh + j * H;
    for (int m = 0; m < H; ++m) { float bb = b2p[m]; cc2 += w1r[m] * bb; cwh += whr[m] * bb; }
    c2_v[r] = cc2; whb2_v[r] = cwh;
  }

  __syncthreads();

  const int rdo = 8 * l;
  const int wro = (w >> 1) * 512 + ((2 * w + (lg >> 1)) & 3) * 128
                + 8 * l15 + 4 * (lg & 1);
  const float* xrow = xbuf + (l15 & 7) * XSTR;

  unsigned short* bA = inbuf;
  unsigned short* bB = inbuf + BUFN;

  // P_ = a0 for step 0 (dt_prev = 0; Whh2 contribution = 0 since bB zeroed)
  f32x4 P_;
#pragma unroll
  for (int r = 0; r < 4; ++r) P_[r] = __builtin_fmaf(xrow[0], e_v[r], c_v[r]);

  for (int t = 0; t < NSTEP; ++t) {
    const float dt  = dtbuf[t];
    const float xn  = xrow[t + 1];
    const float dt3 = dt * (1.f / 3.f);
    f32x4 a, h1, g, pn, s1, s2, s3, z1, z2;

    // ---- P0: a = P_ + Whh2*ssum_scaled ; h1 = tanh(a) ----
    a = P_;
    MATVEC1(bB, whh2f, a);
#pragma unroll
    for (int r = 0; r < 4; ++r) h1[r] = tanh_fast(a[r]);
    WRITE1(bA, h1);
    if (t == NSTEP - 1) {
      u32x2 p; p.x = cvtpk(h1[0], h1[1]); p.y = cvtpk(h1[2], h1[3]);
      *(u32x2*)(h1buf + wro) = p;
    }
    __syncthreads();

    // ---- P1: Gb = W1*h1 + b1 ; P_next = W_hh*h1 + (x_next*e + c + dt*whb2) ----
    g = b1_v;
#pragma unroll
    for (int r = 0; r < 4; ++r)
      pn[r] = __builtin_fmaf(dt, whb2_v[r], __builtin_fmaf(xn, e_v[r], c_v[r]));
    MATVEC2(bA, w1f, whhf, g, pn);
#pragma unroll
    for (int r = 0; r < 4; ++r) s1[r] = silu_f(g[r]);
    WRITE1(bB, s1);
    __syncthreads();

    // ---- P2: z1' = W12*s1 + c2 ; s2 = silu(Gb + dt/3 * z1') ----
    z1 = c2_v;
    MATVEC1(bB, w12f, z1);
#pragma unroll
    for (int r = 0; r < 4; ++r) s2[r] = silu_f(__builtin_fmaf(dt3, z1[r], g[r]));
    WRITE1(bA, s2);
    __syncthreads();

    // ---- P3: z2' = W12*s2 + c2 ; s3 = silu(Gb + dt*z2' - dt/3*z1') ----
    z2 = c2_v;
    MATVEC1(bA, w12f, z2);
#pragma unroll
    for (int r = 0; r < 4; ++r)
      s3[r] = silu_f(__builtin_fmaf(dt, z2[r], __builtin_fmaf(-dt3, z1[r], g[r])));
    WRITE1(bB, s3);
    __syncthreads();

    // ---- P4: z3' = W12*s3 + c2 ; s4 = silu(Gb + dt*(z1'-z2'+z3')) ;
    //          ssum_scaled = (s1 + 3(s2+s3) + s4) * dt/8 ----
    {
      f32x4 z3 = c2_v, ss;
      MATVEC1(bB, w12f, z3);
      const float dt8 = dt * 0.125f;
#pragma unroll
      for (int r = 0; r < 4; ++r) {
        float s4 = silu_f(__builtin_fmaf(dt, (z1[r] - z2[r]) + z3[r], g[r]));
        ss[r] = (__builtin_fmaf(3.f, s2[r] + s3[r], s1[r]) + s4) * dt8;
      }
      WRITE1(bA, ss);
    }
    __syncthreads();

    P_ = pn;
    unsigned short* tmp = bA; bA = bB; bB = tmp;
  }

  // ---- epilogue: out = W_out*h1_T + Wout2*ssum_scaled + dtl*(W_out*b2) + b_out ----
  // ssum_scaled (already *dtl/8) is in bB (last step's bA); h1_T in h1buf.
  {
    const int wo   = w & 3;
    const int orow = 16 * wo + l15;
    const int jo   = 16 * wo + 4 * lg;
    const float dtl = dtbuf[NSTEP - 1];

    short8 wout2f[4];
    {
      float acc[4][8];
#pragma unroll
      for (int s = 0; s < 4; ++s)
#pragma unroll
        for (int i = 0; i < 8; ++i) acc[s][i] = 0.f;
      for (int m = 0; m < H; ++m) {
        float a = W_out[orow * H + m];
        const f32x4* wr4 = (const f32x4*)(wtmp + m * H + 8 * lg);
#pragma unroll
        for (int s = 0; s < 4; ++s) {
          const int cs = (s + rot) & 3;
          f32x4 lo = wr4[8 * cs], hi = wr4[8 * cs + 1];
#pragma unroll
          for (int i = 0; i < 4; ++i) {
            acc[s][i]     = __builtin_fmaf(a, lo[i], acc[s][i]);
            acc[s][4 + i] = __builtin_fmaf(a, hi[i], acc[s][4 + i]);
          }
        }
      }
#pragma unroll
      for (int s = 0; s < 4; ++s) {
        short8 f;
#pragma unroll
        for (int i = 0; i < 8; ++i) f[i] = (short)f2bf(acc[s][i]);
        wout2f[s] = f;
      }
    }
    short8 wof[4];
#pragma unroll
    for (int s = 0; s < 4; ++s) {
      const int cs = (s + rot) & 3;
      const float* p = W_out + orow * H + 32 * cs + 8 * lg;
      short8 f;
#pragma unroll
      for (int i = 0; i < 8; ++i) f[i] = (short)f2bf(p[i]);
      wof[s] = f;
    }
    f32x4 acc1, acc2;
#pragma unroll
    for (int r = 0; r < 4; ++r) {
      const float* wr = W_out + (jo + r) * H;
      float wb = 0.f;
      for (int m = 0; m < H; ++m) wb = __builtin_fmaf(wr[m], b2p[m], wb);
      acc1[r] = __builtin_fmaf(dtl, wb, b_out[jo + r]);
      acc2[r] = 0.f;
    }
    MATVEC1(h1buf, wof, acc1);
    MATVEC1(bB, wout2f, acc2);
    if (w < 4 && l15 < 8) {
#pragma unroll
      for (int r = 0; r < 4; ++r)
        out[(b0 + l15) * D_OUT + jo + r] = acc1[r] + acc2[r];
    }
  }
}

extern "C" void kernel_launch(void* const* d_in, const int* in_sizes, int n_in,
                              void* d_out, int out_size, void* d_ws, size_t ws_size,
                              hipStream_t stream) {
  (void)in_sizes; (void)n_in; (void)ws_size; (void)d_ws; (void)out_size;
  const float* x     = (const float*)d_in[0];
  const float* span  = (const float*)d_in[1];
  const float* W_emb = (const float*)d_in[2];
  const float* b_emb = (const float*)d_in[3];
  const float* W_ih  = (const float*)d_in[4];
  const float* b_ih  = (const float*)d_in[5];
  const float* W_hh  = (const float*)d_in[6];
  const float* b_hh  = (const float*)d_in[7];
  const float* W1    = (const float*)d_in[8];
  const float* b1    = (const float*)d_in[9];
  const float* W2    = (const float*)d_in[10];
  const float* b2    = (const float*)d_in[11];
  const float* W_out = (const float*)d_in[12];
  const float* b_out = (const float*)d_in[13];
  float* out = (float*)d_out;

  rnnode_kernel<<<dim3(256), dim3(512), 0, stream>>>(
      x, span, W_emb, b_emb, W_ih, b_ih, W_hh, b_hh,
      W1, b1, W2, b2, W_out, b_out, out);
}

// Round 9
// 741.035 us; speedup vs baseline: 1.2223x; 1.2046x over previous
//
#include <hip/hip_runtime.h>
#include <hip/hip_bf16.h>

#define T_LEN 512
#define NSTEP 511
#define H 128
#define D_IN 64
#define D_OUT 64
#define XSTR 513
#define BUFN 2048   // ushorts per activation buffer (16 b-cols x 128 k)

typedef __attribute__((ext_vector_type(8))) short short8;
typedef __attribute__((ext_vector_type(4))) float f32x4;

// Activation tile layout (bf16): elem (b in 0..15, k in 0..127) ->
//   ushort idx = (k>>5)*512 + ((k>>3)&3)*128 + b*8 + (k&7)
// Read: lane l takes short8 at 8*l + 512*s (byte 16*l) -> linear, conflict-free.
// A-frag f[i] of chunk s = W[row][32s + 8lg + i]  (validated convention r2-r8).
//
// SPLIT-ACTIVATION (r9): MFMA D-frag cols never mix through the chain, so pad
// cols (l15>=8) are dead values. DPP row_mirror folds real cols' rows {2,3}
// onto pad lanes; every lane then runs tanh/silu on 2 REAL values (not 4),
// halving transcendental issue, and writes one b32 to its own slot.
// Pad columns of the tiles stay 0 (zero-init, never written).

__device__ __forceinline__ float exp2_f(float x) {
  float r; asm("v_exp_f32 %0, %1" : "=v"(r) : "v"(x)); return r;
}
__device__ __forceinline__ float rcp_f(float x) {
  float r; asm("v_rcp_f32 %0, %1" : "=v"(r) : "v"(x)); return r;
}
__device__ __forceinline__ unsigned int cvtpk(float a, float b) {
  unsigned int r; asm("v_cvt_pk_bf16_f32 %0, %1, %2" : "=v"(r) : "v"(a), "v"(b)); return r;
}
__device__ __forceinline__ unsigned short f2bf(float f) {   // prologue-path only
  unsigned int x = __float_as_uint(f);
  x += 0x7fffu + ((x >> 16) & 1u);
  return (unsigned short)(x >> 16);
}
__device__ __forceinline__ float tanh_fast(float x) {
  float e = exp2_f(x * 2.8853900817779268f);   // e^(2x)
  float r = rcp_f(e + 1.0f);
  return __builtin_fmaf(-2.0f, r, 1.0f);
}
__device__ __forceinline__ float silu_f(float x) {
  float e = exp2_f(x * -1.4426950408889634f);  // e^(-x)
  return x * rcp_f(1.0f + e);
}
__device__ __forceinline__ float mirror16(float v) {  // lane (lg,l15) <-> (lg,15-l15)
  return __int_as_float(
      __builtin_amdgcn_mov_dpp(__float_as_int(v), 0x140, 0xF, 0xF, false));
}

#define MFMA16(A, B, C) __builtin_amdgcn_mfma_f32_16x16x32_bf16(A, B, C, 0, 0, 0)

#define MATVEC1(BUF, WF, A)                                                   \
  {                                                                           \
    const unsigned short* _b = (BUF) + rdo;                                   \
    short8 q0 = *(const short8*)(_b);                                         \
    short8 q1 = *(const short8*)(_b + 512);                                   \
    short8 q2 = *(const short8*)(_b + 1024);                                  \
    short8 q3 = *(const short8*)(_b + 1536);                                  \
    A = MFMA16(WF[0], q0, A);                                                 \
    A = MFMA16(WF[1], q1, A);                                                 \
    A = MFMA16(WF[2], q2, A);                                                 \
    A = MFMA16(WF[3], q3, A);                                                 \
  }

// two matmuls sharing one B-tile read
#define MATVEC2(BUF, WF0, WF1, A0, A1)                                        \
  {                                                                           \
    const unsigned short* _b = (BUF) + rdo;                                   \
    short8 q0 = *(const short8*)(_b);                                         \
    short8 q1 = *(const short8*)(_b + 512);                                   \
    short8 q2 = *(const short8*)(_b + 1024);                                  \
    short8 q3 = *(const short8*)(_b + 1536);                                  \
    A0 = MFMA16(WF0[0], q0, A0);                                              \
    A1 = MFMA16(WF1[0], q0, A1);                                              \
    A0 = MFMA16(WF0[1], q1, A0);                                              \
    A1 = MFMA16(WF1[1], q1, A1);                                              \
    A0 = MFMA16(WF0[2], q2, A0);                                              \
    A1 = MFMA16(WF1[2], q2, A1);                                              \
    A0 = MFMA16(WF0[3], q3, A0);                                              \
    A1 = MFMA16(WF1[3], q3, A1);                                              \
  }

// fold D-frag V (4-wide, own col) into this lane's 2 real slot values
#define SPLIT2(V, S0, S1)                                                     \
  {                                                                           \
    float _m2 = mirror16(V[2]);                                               \
    float _m3 = mirror16(V[3]);                                               \
    S0 = isreal ? V[0] : _m2;                                                 \
    S1 = isreal ? V[1] : _m3;                                                 \
  }

#define WRITES(BUF, S0, S1)                                                   \
  { *(unsigned int*)((BUF) + wro2) = cvtpk(S0, S1); }

__global__ __launch_bounds__(512, 2) void rnnode_kernel(
    const float* __restrict__ x,     const float* __restrict__ span,
    const float* __restrict__ W_emb, const float* __restrict__ b_emb,
    const float* __restrict__ W_ih,  const float* __restrict__ b_ih,
    const float* __restrict__ W_hh,  const float* __restrict__ b_hh,
    const float* __restrict__ W1,    const float* __restrict__ b1p,
    const float* __restrict__ W2,    const float* __restrict__ b2p,
    const float* __restrict__ W_out, const float* __restrict__ b_out,
    float* __restrict__ out) {
  __shared__ __align__(16) unsigned short inbuf[2 * BUFN];
  __shared__ __align__(16) unsigned short h1buf[BUFN];
  __shared__ __align__(16) float wtmp[H * H];     // fp32 W2 (prologue + epilogue)
  __shared__ float xbuf[8 * XSTR];
  __shared__ float dtbuf[NSTEP];

  const int tid = threadIdx.x;
  const int w   = tid >> 6;     // wave 0..7, owns j-rows [16w, 16w+16)
  const int l   = tid & 63;
  const int l15 = l & 15;       // b-col
  const int lg  = l >> 4;
  const int b0  = blockIdx.x * 8;

  const bool isreal = (l15 < 8);
  const int  c_s  = isreal ? l15 : 15 - l15;            // owned real col
  const int  k0   = 16 * w + 4 * lg + (isreal ? 0 : 2); // owned row pair base
  const int  wro2 = ((k0 >> 5) * 512) + (((k0 >> 3) & 3) * 128)
                  + 8 * c_s + (k0 & 7);                 // ushort offset (even)

  // ---- stage x, dt, W2 -> wtmp, zero activation buffers (h0 = 0) ----
  for (int i = tid; i < 8 * T_LEN; i += 512) {
    int b = i >> 9, t = i & (T_LEN - 1);
    xbuf[b * XSTR + t] = x[(b0 + b) * T_LEN + t];
  }
  for (int t = tid; t < NSTEP; t += 512) dtbuf[t] = span[t + 1] - span[t];
  for (int i = tid; i < 2 * BUFN; i += 512) inbuf[i] = 0;
  for (int i = tid; i < BUFN; i += 512) h1buf[i] = 0;
  for (int i = tid; i < H * H; i += 512) wtmp[i] = W2[i];
  __syncthreads();

  const int row = 16 * w + l15;

  // ---- fused weight products W12 = W1*W2, Whh2 = W_hh*W2 (fp32 -> bf16 frags) ----
  short8 w12f[4], whh2f[4];
  {
    float acc[4][8];
#pragma unroll
    for (int s = 0; s < 4; ++s)
#pragma unroll
      for (int i = 0; i < 8; ++i) acc[s][i] = 0.f;
    for (int m = 0; m < H; ++m) {
      float a = W1[row * H + m];
      const f32x4* wr4 = (const f32x4*)(wtmp + m * H + 8 * lg);
#pragma unroll
      for (int s = 0; s < 4; ++s) {
        f32x4 lo = wr4[8 * s], hi = wr4[8 * s + 1];
#pragma unroll
        for (int i = 0; i < 4; ++i) {
          acc[s][i]     = __builtin_fmaf(a, lo[i], acc[s][i]);
          acc[s][4 + i] = __builtin_fmaf(a, hi[i], acc[s][4 + i]);
        }
      }
    }
#pragma unroll
    for (int s = 0; s < 4; ++s) {
      short8 f;
#pragma unroll
      for (int i = 0; i < 8; ++i) f[i] = (short)f2bf(acc[s][i]);
      w12f[s] = f;
    }
#pragma unroll
    for (int s = 0; s < 4; ++s)
#pragma unroll
      for (int i = 0; i < 8; ++i) acc[s][i] = 0.f;
    for (int m = 0; m < H; ++m) {
      float a = W_hh[row * H + m];
      const f32x4* wr4 = (const f32x4*)(wtmp + m * H + 8 * lg);
#pragma unroll
      for (int s = 0; s < 4; ++s) {
        f32x4 lo = wr4[8 * s], hi = wr4[8 * s + 1];
#pragma unroll
        for (int i = 0; i < 4; ++i) {
          acc[s][i]     = __builtin_fmaf(a, lo[i], acc[s][i]);
          acc[s][4 + i] = __builtin_fmaf(a, hi[i], acc[s][4 + i]);
        }
      }
    }
#pragma unroll
    for (int s = 0; s < 4; ++s) {
      short8 f;
#pragma unroll
      for (int i = 0; i < 8; ++i) f[i] = (short)f2bf(acc[s][i]);
      whh2f[s] = f;
    }
  }

  // ---- direct weight frags (bf16) ----
  short8 whhf[4], w1f[4];
#pragma unroll
  for (int s = 0; s < 4; ++s) {
    const float* p; short8 f;
    p = W_hh + row * H + 32 * s + 8 * lg;
#pragma unroll
    for (int i = 0; i < 8; ++i) f[i] = (short)f2bf(p[i]);
    whhf[s] = f;
    p = W1 + row * H + 32 * s + 8 * lg;
#pragma unroll
    for (int i = 0; i < 8; ++i) f[i] = (short)f2bf(p[i]);
    w1f[s] = f;
  }

  // ---- per-row vectors: e = W_ih*W_emb, c = W_ih*b_emb + b_ih + b_hh,
  //      c2 = W1*b2, whb2 = W_hh*b2, b1 ----
  f32x4 e_v, c_v, b1_v, c2_v, whb2_v;
#pragma unroll
  for (int r = 0; r < 4; ++r) {
    int j = 16 * w + 4 * lg + r;
    float e = 0.f, c = 0.f;
    const float* wr = W_ih + j * D_IN;
    for (int d = 0; d < D_IN; ++d) { float v = wr[d]; e += v * W_emb[d]; c += v * b_emb[d]; }
    e_v[r] = e; c_v[r] = c + b_ih[j] + b_hh[j];
    b1_v[r] = b1p[j];
    float cc2 = 0.f, cwh = 0.f;
    const float* w1r = W1 + j * H;
    const float* whr = W_hh + j * H;
    for (int m = 0; m < H; ++m) { float bb = b2p[m]; cc2 += w1r[m] * bb; cwh += whr[m] * bb; }
    c2_v[r] = cc2; whb2_v[r] = cwh;
  }

  __syncthreads();

  const int rdo = 8 * l;
  const float* xrow = xbuf + (l15 & 7) * XSTR;

  unsigned short* bA = inbuf;
  unsigned short* bB = inbuf + BUFN;

  // P_ = a0 for step 0 (dt_prev = 0; Whh2 contribution = 0 since bB zeroed)
  f32x4 P_;
#pragma unroll
  for (int r = 0; r < 4; ++r) P_[r] = __builtin_fmaf(xrow[0], e_v[r], c_v[r]);

  for (int t = 0; t < NSTEP; ++t) {
    const float dt  = dtbuf[t];
    const float xn  = xrow[t + 1];
    const float dt3 = dt * (1.f / 3.f);
    const float dt8 = dt * 0.125f;
    f32x4 a, pn;
    float g0, g1, s10, s11, s20, s21, s30, s31, z10, z11, z20, z21;

    // ---- P0: a = P_ + Whh2*ssum_scaled ; h1 = tanh(a) ----
    a = P_;
    MATVEC1(bB, whh2f, a);
    {
      float a0, a1;
      SPLIT2(a, a0, a1);
      a0 = tanh_fast(a0); a1 = tanh_fast(a1);
      WRITES(bA, a0, a1);
      if (t == NSTEP - 1) *(unsigned int*)(h1buf + wro2) = cvtpk(a0, a1);
    }
    __syncthreads();

    // ---- P1: Gb = W1*h1 + b1 ; P_next = W_hh*h1 + (x_next*e + c + dt*whb2) ----
    a = b1_v;
#pragma unroll
    for (int r = 0; r < 4; ++r)
      pn[r] = __builtin_fmaf(dt, whb2_v[r], __builtin_fmaf(xn, e_v[r], c_v[r]));
    MATVEC2(bA, w1f, whhf, a, pn);
    SPLIT2(a, g0, g1);
    s10 = silu_f(g0); s11 = silu_f(g1);
    WRITES(bB, s10, s11);
    __syncthreads();

    // ---- P2: z1' = W12*s1 + c2 ; s2 = silu(g + dt/3 * z1') ----
    a = c2_v;
    MATVEC1(bB, w12f, a);
    SPLIT2(a, z10, z11);
    {
      float r0 = __builtin_fmaf(dt3, z10, g0);
      float r1 = __builtin_fmaf(dt3, z11, g1);
      s20 = silu_f(r0); s21 = silu_f(r1);
    }
    WRITES(bA, s20, s21);
    __syncthreads();

    // ---- P3: z2' = W12*s2 + c2 ; s3 = silu(g + dt*z2' - dt/3*z1') ----
    a = c2_v;
    MATVEC1(bA, w12f, a);
    SPLIT2(a, z20, z21);
    {
      float r0 = __builtin_fmaf(dt, z20, __builtin_fmaf(-dt3, z10, g0));
      float r1 = __builtin_fmaf(dt, z21, __builtin_fmaf(-dt3, z11, g1));
      s30 = silu_f(r0); s31 = silu_f(r1);
    }
    WRITES(bB, s30, s31);
    __syncthreads();

    // ---- P4: z3' = W12*s3 + c2 ; s4 = silu(g + dt*(z1'-z2'+z3')) ;
    //          ssum_scaled = (s1 + 3(s2+s3) + s4) * dt/8 ----
    a = c2_v;
    MATVEC1(bB, w12f, a);
    {
      float z30, z31;
      SPLIT2(a, z30, z31);
      float r0 = __builtin_fmaf(dt, (z10 - z20) + z30, g0);
      float r1 = __builtin_fmaf(dt, (z11 - z21) + z31, g1);
      float s40 = silu_f(r0), s41 = silu_f(r1);
      float ss0 = (__builtin_fmaf(3.f, s20 + s30, s10) + s40) * dt8;
      float ss1 = (__builtin_fmaf(3.f, s21 + s31, s11) + s41) * dt8;
      WRITES(bA, ss0, ss1);
    }
    __syncthreads();

    P_ = pn;
    unsigned short* tmp = bA; bA = bB; bB = tmp;
  }

  // ---- epilogue: out = W_out*h1_T + Wout2*ssum_scaled + dtl*(W_out*b2) + b_out ----
  // ssum_scaled (already *dtl/8) is in bB (last step's bA); h1_T in h1buf.
  {
    const int wo   = w & 3;
    const int orow = 16 * wo + l15;
    const int jo   = 16 * wo + 4 * lg;
    const float dtl = dtbuf[NSTEP - 1];

    short8 wout2f[4];
    {
      float acc[4][8];
#pragma unroll
      for (int s = 0; s < 4; ++s)
#pragma unroll
        for (int i = 0; i < 8; ++i) acc[s][i] = 0.f;
      for (int m = 0; m < H; ++m) {
        float a = W_out[orow * H + m];
        const f32x4* wr4 = (const f32x4*)(wtmp + m * H + 8 * lg);
#pragma unroll
        for (int s = 0; s < 4; ++s) {
          f32x4 lo = wr4[8 * s], hi = wr4[8 * s + 1];
#pragma unroll
          for (int i = 0; i < 4; ++i) {
            acc[s][i]     = __builtin_fmaf(a, lo[i], acc[s][i]);
            acc[s][4 + i] = __builtin_fmaf(a, hi[i], acc[s][4 + i]);
          }
        }
      }
#pragma unroll
      for (int s = 0; s < 4; ++s) {
        short8 f;
#pragma unroll
        for (int i = 0; i < 8; ++i) f[i] = (short)f2bf(acc[s][i]);
        wout2f[s] = f;
      }
    }
    short8 wof[4];
#pragma unroll
    for (int s = 0; s < 4; ++s) {
      const float* p = W_out + orow * H + 32 * s + 8 * lg;
      short8 f;
#pragma unroll
      for (int i = 0; i < 8; ++i) f[i] = (short)f2bf(p[i]);
      wof[s] = f;
    }
    f32x4 acc1, acc2;
#pragma unroll
    for (int r = 0; r < 4; ++r) {
      const float* wr = W_out + (jo + r) * H;
      float wb = 0.f;
      for (int m = 0; m < H; ++m) wb = __builtin_fmaf(wr[m], b2p[m], wb);
      acc1[r] = __builtin_fmaf(dtl, wb, b_out[jo + r]);
      acc2[r] = 0.f;
    }
    MATVEC1(h1buf, wof, acc1);
    MATVEC1(bB, wout2f, acc2);
    if (w < 4 && l15 < 8) {
#pragma unroll
      for (int r = 0; r < 4; ++r)
        out[(b0 + l15) * D_OUT + jo + r] = acc1[r] + acc2[r];
    }
  }
}

extern "C" void kernel_launch(void* const* d_in, const int* in_sizes, int n_in,
                              void* d_out, int out_size, void* d_ws, size_t ws_size,
                              hipStream_t stream) {
  (void)in_sizes; (void)n_in; (void)ws_size; (void)d_ws; (void)out_size;
  const float* x     = (const float*)d_in[0];
  const float* span  = (const float*)d_in[1];
  const float* W_emb = (const float*)d_in[2];
  const float* b_emb = (const float*)d_in[3];
  const float* W_ih  = (const float*)d_in[4];
  const float* b_ih  = (const float*)d_in[5];
  const float* W_hh  = (const float*)d_in[6];
  const float* b_hh  = (const float*)d_in[7];
  const float* W1    = (const float*)d_in[8];
  const float* b1    = (const float*)d_in[9];
  const float* W2    = (const float*)d_in[10];
  const float* b2    = (const float*)d_in[11];
  const float* W_out = (const float*)d_in[12];
  const float* b_out = (const float*)d_in[13];
  float* out = (float*)d_out;

  rnnode_kernel<<<dim3(256), dim3(512), 0, stream>>>(
      x, span, W_emb, b_emb, W_ih, b_ih, W_hh, b_hh,
      W1, b1, W2, b2, W_out, b_out, out);
}